// Round 11
// baseline (2614.919 us; speedup 1.0000x reference)
//
#include <hip/hip_runtime.h>
#include <math.h>

typedef unsigned short ushort_t;
typedef __bf16 bf16x8 __attribute__((ext_vector_type(8)));
typedef float f32x4 __attribute__((ext_vector_type(4)));

__device__ __forceinline__ float bf2f(unsigned int u) {
    union { unsigned int i; float f; } v; v.i = u << 16; return v.f;
}
__device__ __forceinline__ ushort_t f2bf(float f) {
    union { float f; unsigned int i; } v; v.f = f;
    unsigned int u = v.i;
    unsigned int r = u + 0x7fffu + ((u >> 16) & 1u);
    return (ushort_t)(r >> 16);
}

// ---------------------------------------------------------------------------
// GEMM: C[M,N] = A[M,K] @ W[K,N] + bias -> bf16 ws.  A fp32 (ABF16=false) or
// bf16 ws (true); W,bias fp32 C-order [K,N]. MODE 2 adds exact GELU.
// BM=BN=128, BK=32, 4 waves, mfma_f32_16x16x32_bf16. Bit-validated vs
// independent VALU and naive-scalar engines (R3-R7).
// ---------------------------------------------------------------------------
#define BM 128
#define BN 128
#define BK 32

template <int MODE, bool ABF16>
__global__ void __launch_bounds__(256) gemm_kernel(
    const void* __restrict__ Av, const float* __restrict__ W,
    const float* __restrict__ bias, ushort_t* __restrict__ Cout,
    int M, int N, int K)
{
    __shared__ __align__(16) ushort_t As[BM][BK];
    __shared__ __align__(16) ushort_t Bs[BN][BK + 8];

    const int tid = threadIdx.x;
    const int m0 = blockIdx.y * BM, n0 = blockIdx.x * BN;
    const int wave = tid >> 6, lane = tid & 63;
    const int wm = wave >> 1, wn = wave & 1;
    const int lr = lane & 15;
    const int lk = (lane >> 4) * 8;

    f32x4 acc[4][4];
#pragma unroll
    for (int i = 0; i < 4; i++)
#pragma unroll
        for (int j = 0; j < 4; j++) acc[i][j] = (f32x4){0.f, 0.f, 0.f, 0.f};

    for (int k0 = 0; k0 < K; k0 += BK) {
        if (ABF16) {
            const ushort_t* A = (const ushort_t*)Av;
#pragma unroll
            for (int r = 0; r < 2; r++) {
                int v = r * 256 + tid;
                int row = v >> 2;
                int c8 = (v & 3) * 8;
                uint4 d = *(const uint4*)(&A[(size_t)(m0 + row) * K + k0 + c8]);
                *(uint4*)(&As[row][c8]) = d;
            }
        } else {
            const float* A = (const float*)Av;
#pragma unroll
            for (int r = 0; r < 4; r++) {
                int v = r * 256 + tid;
                int row = v >> 3;
                int c4 = (v & 7) * 4;
                float4 d = *(const float4*)(&A[(size_t)(m0 + row) * K + k0 + c4]);
                union { ushort_t u[4]; unsigned long long ll; } pk;
                pk.u[0] = f2bf(d.x); pk.u[1] = f2bf(d.y);
                pk.u[2] = f2bf(d.z); pk.u[3] = f2bf(d.w);
                *(unsigned long long*)(&As[row][c4]) = pk.ll;
            }
        }
        // W [K,N] C-order: scatter-transpose into Bs[n][k]
#pragma unroll
        for (int r = 0; r < 4; r++) {
            int v = r * 256 + tid;
            int k = v >> 5;
            int n4 = (v & 31) * 4;
            float4 d = *(const float4*)(&W[(size_t)(k0 + k) * N + n0 + n4]);
            Bs[n4 + 0][k] = f2bf(d.x);
            Bs[n4 + 1][k] = f2bf(d.y);
            Bs[n4 + 2][k] = f2bf(d.z);
            Bs[n4 + 3][k] = f2bf(d.w);
        }
        __syncthreads();

        bf16x8 af[4], bfr[4];
#pragma unroll
        for (int i = 0; i < 4; i++)
            af[i] = *(const bf16x8*)(&As[wm * 64 + i * 16 + lr][lk]);
#pragma unroll
        for (int j = 0; j < 4; j++)
            bfr[j] = *(const bf16x8*)(&Bs[wn * 64 + j * 16 + lr][lk]);
#pragma unroll
        for (int i = 0; i < 4; i++)
#pragma unroll
            for (int j = 0; j < 4; j++)
                acc[i][j] = __builtin_amdgcn_mfma_f32_16x16x32_bf16(af[i], bfr[j], acc[i][j], 0, 0, 0);
        __syncthreads();
    }

    const int rq = (lane >> 4) * 4;
#pragma unroll
    for (int j = 0; j < 4; j++) {
        int col = n0 + wn * 64 + j * 16 + lr;
        float bv = bias[col];
#pragma unroll
        for (int i = 0; i < 4; i++) {
#pragma unroll
            for (int r = 0; r < 4; r++) {
                int row = m0 + wm * 64 + i * 16 + rq + r;
                float v = acc[i][j][r] + bv;
                if (MODE == 2) {
                    v = 0.5f * v * (1.0f + erff(v * 0.70710678118654752f));
                }
                Cout[(size_t)row * N + col] = f2bf(v);
            }
        }
    }
}

// ---------------------------------------------------------------------------
// Flash attention, hd=64, D=1024, H=16. Q/K/V bf16 ws C-order [b,l,h*64+d].
// mask fp32 [4,1,1,Lk] (flat b*Lk+k) or null. 256 thr: one (b,h), 32 q rows.
// ---------------------------------------------------------------------------
#define TQ 32
#define TK 32

__global__ void __launch_bounds__(256) flash_attn_kernel(
    const ushort_t* __restrict__ Q, const ushort_t* __restrict__ Kt,
    const ushort_t* __restrict__ Vt, const float* __restrict__ mask,
    ushort_t* __restrict__ O, int Lq, int Lk, float scale)
{
    __shared__ __align__(16) ushort_t qs[TQ][72];
    __shared__ __align__(16) ushort_t ks[TK][72];
    __shared__ __align__(16) ushort_t vs[TK][72];
    __shared__ __align__(16) float ss[TQ][TK + 1];

    const int tid = threadIdx.x;
    const int b = blockIdx.y >> 4;
    const int h = blockIdx.y & 15;
    const int q0 = blockIdx.x * TQ;
    const size_t qbase = ((size_t)b * Lq) * 1024 + h * 64;
    const size_t kbase = ((size_t)b * Lk) * 1024 + h * 64;

    {
        int row = tid >> 3, c8 = (tid & 7) * 8;
        *(uint4*)(&qs[row][c8]) = *(const uint4*)(&Q[qbase + (size_t)(q0 + row) * 1024 + c8]);
    }
    const int qr = tid >> 3;
    const int g = tid & 7;
    float m_i = -1e30f, l_i = 0.f;
    float oacc[8];
#pragma unroll
    for (int i = 0; i < 8; i++) oacc[i] = 0.f;
    __syncthreads();

    for (int kt = 0; kt < Lk; kt += TK) {
        {
            int row = tid >> 3, c8 = (tid & 7) * 8;
            *(uint4*)(&ks[row][c8]) = *(const uint4*)(&Kt[kbase + (size_t)(kt + row) * 1024 + c8]);
            *(uint4*)(&vs[row][c8]) = *(const uint4*)(&Vt[kbase + (size_t)(kt + row) * 1024 + c8]);
        }
        __syncthreads();

        float sc[4];
#pragma unroll
        for (int j = 0; j < 4; j++) {
            int kc = g * 4 + j;
            float dot = 0.f;
#pragma unroll
            for (int dd = 0; dd < 64; dd += 8) {
                uint4 qa = *(const uint4*)(&qs[qr][dd]);
                uint4 ka = *(const uint4*)(&ks[kc][dd]);
                const unsigned int* qp = (const unsigned int*)&qa;
                const unsigned int* kp = (const unsigned int*)&ka;
#pragma unroll
                for (int e = 0; e < 4; e++) {
                    dot += bf2f(qp[e] & 0xffffu) * bf2f(kp[e] & 0xffffu);
                    dot += bf2f(qp[e] >> 16) * bf2f(kp[e] >> 16);
                }
            }
            float s = dot * scale;
            if (mask) s += mask[(size_t)b * Lk + kt + kc];
            sc[j] = s;
        }
        float tmax = fmaxf(fmaxf(sc[0], sc[1]), fmaxf(sc[2], sc[3]));
#pragma unroll
        for (int o = 1; o < 8; o <<= 1) tmax = fmaxf(tmax, __shfl_xor(tmax, o, 64));
        float m_new = fmaxf(m_i, tmax);
        float alpha = __expf(m_i - m_new);
        float psum = 0.f;
#pragma unroll
        for (int j = 0; j < 4; j++) {
            float p = __expf(sc[j] - m_new);
            ss[qr][g * 4 + j] = p;
            psum += p;
        }
#pragma unroll
        for (int o = 1; o < 8; o <<= 1) psum += __shfl_xor(psum, o, 64);
        l_i = l_i * alpha + psum;
        m_i = m_new;
#pragma unroll
        for (int i = 0; i < 8; i++) oacc[i] *= alpha;
        __syncthreads();

        const int dbase = g * 8;
#pragma unroll
        for (int k = 0; k < TK; k++) {
            float p = ss[qr][k];
            uint4 va = *(const uint4*)(&vs[k][dbase]);
            const unsigned int* vp = (const unsigned int*)&va;
#pragma unroll
            for (int i = 0; i < 4; i++) {
                oacc[2 * i]     += p * bf2f(vp[i] & 0xffffu);
                oacc[2 * i + 1] += p * bf2f(vp[i] >> 16);
            }
        }
        __syncthreads();
    }

    float inv = 1.0f / fmaxf(l_i, 1e-30f);
    ushort_t outv[8];
#pragma unroll
    for (int i = 0; i < 8; i++) outv[i] = f2bf(oacc[i] * inv);
    *(uint4*)(&O[qbase + (size_t)(q0 + qr) * 1024 + g * 8]) = *(uint4*)outv;
}

// ---------------------------------------------------------------------------
// Fused residual + LayerNorm (rows of 1024). H bf16 + Res (fp32 if RES_F32
// else bf16 ws) -> LN (gamma/beta fp32) -> OUT_F32 ? fp32 : bf16.
// ---------------------------------------------------------------------------
template <bool RES_F32, bool OUT_F32>
__global__ void __launch_bounds__(256) ln_kernel(
    const ushort_t* __restrict__ Hbuf, const void* __restrict__ Res,
    const float* __restrict__ gamma, const float* __restrict__ beta,
    void* __restrict__ Out)
{
    const int row = blockIdx.x;
    const int tid = threadIdx.x;
    const size_t base = (size_t)row * 1024 + tid * 4;

    uint2 hh = *(const uint2*)(Hbuf + base);
    float v[4];
    v[0] = bf2f(hh.x & 0xffffu);
    v[1] = bf2f(hh.x >> 16);
    v[2] = bf2f(hh.y & 0xffffu);
    v[3] = bf2f(hh.y >> 16);
    if (RES_F32) {
        float4 rv = *(const float4*)((const float*)Res + base);
        v[0] += rv.x; v[1] += rv.y; v[2] += rv.z; v[3] += rv.w;
    } else {
        uint2 rr = *(const uint2*)((const ushort_t*)Res + base);
        v[0] += bf2f(rr.x & 0xffffu);
        v[1] += bf2f(rr.x >> 16);
        v[2] += bf2f(rr.y & 0xffffu);
        v[3] += bf2f(rr.y >> 16);
    }

    float s = v[0] + v[1] + v[2] + v[3];
    float s2 = v[0]*v[0] + v[1]*v[1] + v[2]*v[2] + v[3]*v[3];
#pragma unroll
    for (int o = 1; o < 64; o <<= 1) {
        s += __shfl_xor(s, o, 64);
        s2 += __shfl_xor(s2, o, 64);
    }
    __shared__ float red[8];
    const int wv = tid >> 6, ln_ = tid & 63;
    if (ln_ == 0) { red[wv] = s; red[wv + 4] = s2; }
    __syncthreads();
    s = red[0] + red[1] + red[2] + red[3];
    s2 = red[4] + red[5] + red[6] + red[7];
    const float mu = s * (1.0f / 1024.0f);
    const float var = s2 * (1.0f / 1024.0f) - mu * mu;
    const float rstd = rsqrtf(var + 1e-5f);

    float4 gv = *(const float4*)(&gamma[tid * 4]);
    float4 bv = *(const float4*)(&beta[tid * 4]);
    float o0 = (v[0] - mu) * rstd * gv.x + bv.x;
    float o1 = (v[1] - mu) * rstd * gv.y + bv.y;
    float o2 = (v[2] - mu) * rstd * gv.z + bv.z;
    float o3 = (v[3] - mu) * rstd * gv.w + bv.w;

    if (OUT_F32) {
        float4 of = {o0, o1, o2, o3};
        *(float4*)((float*)Out + base) = of;
    } else {
        ushort_t ob[4] = {f2bf(o0), f2bf(o1), f2bf(o2), f2bf(o3)};
        *(uint2*)((ushort_t*)Out + base) = *(uint2*)ob;
    }
}

// ---------------------------------------------------------------------------
// Launch: bit-validated C-order pipeline; FINAL OUTPUT WRITTEN AS FP32
// (the reference returns float32 — the harness reads d_out as np.float32;
// "bf16" in the error label is a hardcoded f-string, not the dtype).
// ws: Bq[0,8) Bk[8,24) Bv[24,40) Ba[40,48) Bh[48,56) Bx1[56,64) Bx2[64,72)
//     Bi=Bk[8,40)
// ---------------------------------------------------------------------------
extern "C" void kernel_launch(void* const* d_in, const int* in_sizes, int n_in,
                              void* d_out, int out_size, void* d_ws, size_t ws_size,
                              hipStream_t stream)
{
    const float* input = (const float*)d_in[0];
    const float* ctx   = (const float*)d_in[1];
    const float* mask  = (const float*)d_in[2];
    const float* cq_w = (const float*)d_in[3],  *cq_b = (const float*)d_in[4];
    const float* ck_w = (const float*)d_in[5],  *ck_b = (const float*)d_in[6];
    const float* cv_w = (const float*)d_in[7],  *cv_b = (const float*)d_in[8];
    const float* co_w = (const float*)d_in[9],  *co_b = (const float*)d_in[10];
    const float* co_g = (const float*)d_in[11], *co_be = (const float*)d_in[12];
    const float* sq_w = (const float*)d_in[13], *sq_b = (const float*)d_in[14];
    const float* sk_w = (const float*)d_in[15], *sk_b = (const float*)d_in[16];
    const float* sv_w = (const float*)d_in[17], *sv_b = (const float*)d_in[18];
    const float* so_w = (const float*)d_in[19], *so_b = (const float*)d_in[20];
    const float* so_g = (const float*)d_in[21], *so_be = (const float*)d_in[22];
    const float* fi_w = (const float*)d_in[23], *fi_b = (const float*)d_in[24];
    const float* fo_w = (const float*)d_in[25], *fo_b = (const float*)d_in[26];
    const float* fo_g = (const float*)d_in[27], *fo_be = (const float*)d_in[28];

    char* p = (char*)d_ws;
    const size_t MB = 1024 * 1024;
    ushort_t* Bq  = (ushort_t*)(p + 0 * MB);
    ushort_t* Bk  = (ushort_t*)(p + 8 * MB);
    ushort_t* Bv  = (ushort_t*)(p + 24 * MB);
    ushort_t* Ba  = (ushort_t*)(p + 40 * MB);
    ushort_t* Bh  = (ushort_t*)(p + 48 * MB);
    ushort_t* Bx1 = (ushort_t*)(p + 56 * MB);
    ushort_t* Bx2 = (ushort_t*)(p + 64 * MB);
    ushort_t* Bi  = Bk;   // FFN inter [8,40)

    const float scale = 0.125f;
    dim3 blk(256);

    // ---- cross attention ----
    gemm_kernel<0, false><<<dim3(8, 32), blk, 0, stream>>>(input, cq_w, cq_b, Bq, 4096, 1024, 1024);
    gemm_kernel<0, false><<<dim3(8, 64), blk, 0, stream>>>(ctx, ck_w, ck_b, Bk, 8192, 1024, 1024);
    gemm_kernel<0, false><<<dim3(8, 64), blk, 0, stream>>>(ctx, cv_w, cv_b, Bv, 8192, 1024, 1024);
    flash_attn_kernel<<<dim3(32, 64), blk, 0, stream>>>(Bq, Bk, Bv, mask, Ba, 1024, 2048, scale);
    gemm_kernel<0, true><<<dim3(8, 32), blk, 0, stream>>>(Ba, co_w, co_b, Bh, 4096, 1024, 1024);
    ln_kernel<true, false><<<dim3(4096), blk, 0, stream>>>(Bh, input, co_g, co_be, Bx1);

    // ---- self attention ----
    gemm_kernel<0, true><<<dim3(8, 32), blk, 0, stream>>>(Bx1, sq_w, sq_b, Bq, 4096, 1024, 1024);
    gemm_kernel<0, true><<<dim3(8, 32), blk, 0, stream>>>(Bx1, sk_w, sk_b, Bk, 4096, 1024, 1024);
    gemm_kernel<0, true><<<dim3(8, 32), blk, 0, stream>>>(Bx1, sv_w, sv_b, Bv, 4096, 1024, 1024);
    flash_attn_kernel<<<dim3(32, 64), blk, 0, stream>>>(Bq, Bk, Bv, nullptr, Ba, 1024, 1024, scale);
    gemm_kernel<0, true><<<dim3(8, 32), blk, 0, stream>>>(Ba, so_w, so_b, Bh, 4096, 1024, 1024);
    ln_kernel<false, false><<<dim3(4096), blk, 0, stream>>>(Bh, Bx1, so_g, so_be, Bx2);

    // ---- FFN ----
    gemm_kernel<2, true><<<dim3(32, 32), blk, 0, stream>>>(Bx2, fi_w, fi_b, Bi, 4096, 4096, 1024);
    gemm_kernel<0, true><<<dim3(8, 32), blk, 0, stream>>>(Bi, fo_w, fo_b, Bh, 4096, 1024, 4096);
    ln_kernel<false, true><<<dim3(4096), blk, 0, stream>>>(Bh, Bx2, fo_g, fo_be, (float*)d_out);
}

// Round 12
// 1391.247 us; speedup vs baseline: 1.8796x; 1.8796x over previous
//
#include <hip/hip_runtime.h>
#include <math.h>

typedef unsigned short ushort_t;
typedef __bf16 bf16x8 __attribute__((ext_vector_type(8)));
typedef float f32x4 __attribute__((ext_vector_type(4)));

__device__ __forceinline__ float bf2f(unsigned int u) {
    union { unsigned int i; float f; } v; v.i = u << 16; return v.f;
}
__device__ __forceinline__ ushort_t f2bf(float f) {
    union { float f; unsigned int i; } v; v.f = f;
    unsigned int u = v.i;
    unsigned int r = u + 0x7fffu + ((u >> 16) & 1u);
    return (ushort_t)(r >> 16);
}

// ---------------------------------------------------------------------------
// GEMM: C[M,N] = A[M,K] @ W[K,N] + bias -> bf16 ws.  A fp32 (ABF16=false) or
// bf16 ws (true); W,bias fp32 C-order [K,N]. MODE 2 adds exact GELU.
// BM=BN=128, BK=32, 4 waves, mfma_f32_16x16x32_bf16. Bit-validated R3-R7.
// ---------------------------------------------------------------------------
#define BM 128
#define BN 128
#define BK 32

template <int MODE, bool ABF16>
__global__ void __launch_bounds__(256) gemm_kernel(
    const void* __restrict__ Av, const float* __restrict__ W,
    const float* __restrict__ bias, ushort_t* __restrict__ Cout,
    int M, int N, int K)
{
    __shared__ __align__(16) ushort_t As[BM][BK];
    __shared__ __align__(16) ushort_t Bs[BN][BK + 8];

    const int tid = threadIdx.x;
    const int m0 = blockIdx.y * BM, n0 = blockIdx.x * BN;
    const int wave = tid >> 6, lane = tid & 63;
    const int wm = wave >> 1, wn = wave & 1;
    const int lr = lane & 15;
    const int lk = (lane >> 4) * 8;

    f32x4 acc[4][4];
#pragma unroll
    for (int i = 0; i < 4; i++)
#pragma unroll
        for (int j = 0; j < 4; j++) acc[i][j] = (f32x4){0.f, 0.f, 0.f, 0.f};

    for (int k0 = 0; k0 < K; k0 += BK) {
        if (ABF16) {
            const ushort_t* A = (const ushort_t*)Av;
#pragma unroll
            for (int r = 0; r < 2; r++) {
                int v = r * 256 + tid;
                int row = v >> 2;
                int c8 = (v & 3) * 8;
                uint4 d = *(const uint4*)(&A[(size_t)(m0 + row) * K + k0 + c8]);
                *(uint4*)(&As[row][c8]) = d;
            }
        } else {
            const float* A = (const float*)Av;
#pragma unroll
            for (int r = 0; r < 4; r++) {
                int v = r * 256 + tid;
                int row = v >> 3;
                int c4 = (v & 7) * 4;
                float4 d = *(const float4*)(&A[(size_t)(m0 + row) * K + k0 + c4]);
                union { ushort_t u[4]; unsigned long long ll; } pk;
                pk.u[0] = f2bf(d.x); pk.u[1] = f2bf(d.y);
                pk.u[2] = f2bf(d.z); pk.u[3] = f2bf(d.w);
                *(unsigned long long*)(&As[row][c4]) = pk.ll;
            }
        }
#pragma unroll
        for (int r = 0; r < 4; r++) {
            int v = r * 256 + tid;
            int k = v >> 5;
            int n4 = (v & 31) * 4;
            float4 d = *(const float4*)(&W[(size_t)(k0 + k) * N + n0 + n4]);
            Bs[n4 + 0][k] = f2bf(d.x);
            Bs[n4 + 1][k] = f2bf(d.y);
            Bs[n4 + 2][k] = f2bf(d.z);
            Bs[n4 + 3][k] = f2bf(d.w);
        }
        __syncthreads();

        bf16x8 af[4], bfr[4];
#pragma unroll
        for (int i = 0; i < 4; i++)
            af[i] = *(const bf16x8*)(&As[wm * 64 + i * 16 + lr][lk]);
#pragma unroll
        for (int j = 0; j < 4; j++)
            bfr[j] = *(const bf16x8*)(&Bs[wn * 64 + j * 16 + lr][lk]);
#pragma unroll
        for (int i = 0; i < 4; i++)
#pragma unroll
            for (int j = 0; j < 4; j++)
                acc[i][j] = __builtin_amdgcn_mfma_f32_16x16x32_bf16(af[i], bfr[j], acc[i][j], 0, 0, 0);
        __syncthreads();
    }

    const int rq = (lane >> 4) * 4;
#pragma unroll
    for (int j = 0; j < 4; j++) {
        int col = n0 + wn * 64 + j * 16 + lr;
        float bv = bias[col];
#pragma unroll
        for (int i = 0; i < 4; i++) {
#pragma unroll
            for (int r = 0; r < 4; r++) {
                int row = m0 + wm * 64 + i * 16 + rq + r;
                float v = acc[i][j][r] + bv;
                if (MODE == 2) {
                    v = 0.5f * v * (1.0f + erff(v * 0.70710678118654752f));
                }
                Cout[(size_t)row * N + col] = f2bf(v);
            }
        }
    }
}

// ---------------------------------------------------------------------------
// MFMA flash attention. hd=64, D=1024, H=16. Q/K/V bf16 ws [b,l,h*64+d].
// Block: 256 thr = 4 waves, one (b,h), 64 q rows (16/wave). K-tiles of 32.
// QK^T: 4 MFMAs (Q A-frags in regs); softmax: quad-local shfl reductions
// (C layout: row=quad*4+reg, col=lane&15); P -> LDS (C->A layout transform,
// m120-verified); PV: 4 MFMAs vs V^T in LDS (XOR-swizzled k to avoid 8-way
// staging-write bank conflicts). mask fp32 [b,Lk] or null.
// ---------------------------------------------------------------------------
__global__ void __launch_bounds__(256) mfma_attn_kernel(
    const ushort_t* __restrict__ Q, const ushort_t* __restrict__ Kt,
    const ushort_t* __restrict__ Vt, const float* __restrict__ mask,
    ushort_t* __restrict__ O, int Lq, int Lk, float scale)
{
    __shared__ __align__(16) ushort_t qs[64][72];
    __shared__ __align__(16) ushort_t ks[32][72];
    __shared__ __align__(16) ushort_t vsT[64][40];   // vsT[d][k^swz(d)]
    __shared__ __align__(16) ushort_t ps[4][16][40]; // per-wave P tile

    const int tid = threadIdx.x;
    const int wave = tid >> 6, lane = tid & 63;
    const int quad = lane >> 4, lc = lane & 15;
    const int b = blockIdx.y >> 4, h = blockIdx.y & 15;
    const int q0 = blockIdx.x * 64;
    const size_t qbase = ((size_t)b * Lq) * 1024 + h * 64;
    const size_t kbase = ((size_t)b * Lk) * 1024 + h * 64;

    // stage Q tile 64x64 (2 vec8 per thread), reused across all k-tiles
#pragma unroll
    for (int r = 0; r < 2; r++) {
        int v = r * 256 + tid;
        int row = v >> 3, c8 = (v & 7) * 8;
        *(uint4*)(&qs[row][c8]) = *(const uint4*)(&Q[qbase + (size_t)(q0 + row) * 1024 + c8]);
    }
    __syncthreads();

    // wave's Q A-frags, held in registers
    bf16x8 qa0 = *(const bf16x8*)(&qs[wave * 16 + lc][quad * 8]);
    bf16x8 qa1 = *(const bf16x8*)(&qs[wave * 16 + lc][32 + quad * 8]);

    f32x4 o[4];
#pragma unroll
    for (int d = 0; d < 4; d++) o[d] = (f32x4){0.f, 0.f, 0.f, 0.f};
    float m_i[4], l_i[4];
#pragma unroll
    for (int r = 0; r < 4; r++) { m_i[r] = -1e30f; l_i[r] = 0.f; }

    for (int kt = 0; kt < Lk; kt += 32) {
        __syncthreads();  // prev iter's ks/vsT reads complete
        {   // stage K [32][64] and V^T [64][32] (swizzled)
            int row = tid >> 3, c8 = (tid & 7) * 8;
            const size_t gk = kbase + (size_t)(kt + row) * 1024 + c8;
            *(uint4*)(&ks[row][c8]) = *(const uint4*)(&Kt[gk]);
            uint4 vv = *(const uint4*)(&Vt[gk]);
            const ushort_t* vp = (const ushort_t*)&vv;
#pragma unroll
            for (int i = 0; i < 8; i++) {
                int d = c8 + i;
                vsT[d][row ^ (((d >> 3) & 3) << 3)] = vp[i];
            }
        }
        __syncthreads();

        // QK^T -> S[16 q][32 k], two C frags
        bf16x8 kb00 = *(const bf16x8*)(&ks[lc][quad * 8]);
        bf16x8 kb01 = *(const bf16x8*)(&ks[lc][32 + quad * 8]);
        bf16x8 kb10 = *(const bf16x8*)(&ks[16 + lc][quad * 8]);
        bf16x8 kb11 = *(const bf16x8*)(&ks[16 + lc][32 + quad * 8]);
        f32x4 s0 = (f32x4){0.f, 0.f, 0.f, 0.f};
        f32x4 s1 = (f32x4){0.f, 0.f, 0.f, 0.f};
        s0 = __builtin_amdgcn_mfma_f32_16x16x32_bf16(qa0, kb00, s0, 0, 0, 0);
        s0 = __builtin_amdgcn_mfma_f32_16x16x32_bf16(qa1, kb01, s0, 0, 0, 0);
        s1 = __builtin_amdgcn_mfma_f32_16x16x32_bf16(qa0, kb10, s1, 0, 0, 0);
        s1 = __builtin_amdgcn_mfma_f32_16x16x32_bf16(qa1, kb11, s1, 0, 0, 0);

        float mk0 = mask ? mask[(size_t)b * Lk + kt + lc] : 0.f;
        float mk1 = mask ? mask[(size_t)b * Lk + kt + 16 + lc] : 0.f;

        float alpha[4];
#pragma unroll
        for (int r = 0; r < 4; r++) {
            float v0 = s0[r] * scale + mk0;
            float v1 = s1[r] * scale + mk1;
            float mx = fmaxf(v0, v1);
#pragma unroll
            for (int off = 1; off < 16; off <<= 1) mx = fmaxf(mx, __shfl_xor(mx, off, 64));
            float mnew = fmaxf(m_i[r], mx);
            alpha[r] = __expf(m_i[r] - mnew);
            m_i[r] = mnew;
            float p0 = __expf(v0 - mnew);
            float p1 = __expf(v1 - mnew);
            ps[wave][quad * 4 + r][lc] = f2bf(p0);
            ps[wave][quad * 4 + r][16 + lc] = f2bf(p1);
            float psum = p0 + p1;
#pragma unroll
            for (int off = 1; off < 16; off <<= 1) psum += __shfl_xor(psum, off, 64);
            l_i[r] = l_i[r] * alpha[r] + psum;
        }
#pragma unroll
        for (int d = 0; d < 4; d++)
#pragma unroll
            for (int r = 0; r < 4; r++) o[d][r] *= alpha[r];

        // PV: A = P (wave-local LDS, in-order DS pipe makes write->read safe)
        bf16x8 pa = *(const bf16x8*)(&ps[wave][lc][quad * 8]);
#pragma unroll
        for (int d = 0; d < 4; d++) {
            int dr = d * 16 + lc;
            bf16x8 vb = *(const bf16x8*)(&vsT[dr][(quad * 8) ^ ((((dr) >> 3) & 3) << 3)]);
            o[d] = __builtin_amdgcn_mfma_f32_16x16x32_bf16(pa, vb, o[d], 0, 0, 0);
        }
    }

    // epilogue: O/l -> global bf16 (C layout: row=quad*4+r, col=d*16+lc)
#pragma unroll
    for (int d = 0; d < 4; d++) {
#pragma unroll
        for (int r = 0; r < 4; r++) {
            float val = o[d][r] / l_i[r];
            O[qbase + (size_t)(q0 + wave * 16 + quad * 4 + r) * 1024 + d * 16 + lc] = f2bf(val);
        }
    }
}

// ---------------------------------------------------------------------------
// Fused residual + LayerNorm (rows of 1024). H bf16 + Res (fp32 if RES_F32
// else bf16 ws) -> LN (gamma/beta fp32) -> OUT_F32 ? fp32 : bf16.
// ---------------------------------------------------------------------------
template <bool RES_F32, bool OUT_F32>
__global__ void __launch_bounds__(256) ln_kernel(
    const ushort_t* __restrict__ Hbuf, const void* __restrict__ Res,
    const float* __restrict__ gamma, const float* __restrict__ beta,
    void* __restrict__ Out)
{
    const int row = blockIdx.x;
    const int tid = threadIdx.x;
    const size_t base = (size_t)row * 1024 + tid * 4;

    uint2 hh = *(const uint2*)(Hbuf + base);
    float v[4];
    v[0] = bf2f(hh.x & 0xffffu);
    v[1] = bf2f(hh.x >> 16);
    v[2] = bf2f(hh.y & 0xffffu);
    v[3] = bf2f(hh.y >> 16);
    if (RES_F32) {
        float4 rv = *(const float4*)((const float*)Res + base);
        v[0] += rv.x; v[1] += rv.y; v[2] += rv.z; v[3] += rv.w;
    } else {
        uint2 rr = *(const uint2*)((const ushort_t*)Res + base);
        v[0] += bf2f(rr.x & 0xffffu);
        v[1] += bf2f(rr.x >> 16);
        v[2] += bf2f(rr.y & 0xffffu);
        v[3] += bf2f(rr.y >> 16);
    }

    float s = v[0] + v[1] + v[2] + v[3];
    float s2 = v[0]*v[0] + v[1]*v[1] + v[2]*v[2] + v[3]*v[3];
#pragma unroll
    for (int o = 1; o < 64; o <<= 1) {
        s += __shfl_xor(s, o, 64);
        s2 += __shfl_xor(s2, o, 64);
    }
    __shared__ float red[8];
    const int wv = tid >> 6, ln_ = tid & 63;
    if (ln_ == 0) { red[wv] = s; red[wv + 4] = s2; }
    __syncthreads();
    s = red[0] + red[1] + red[2] + red[3];
    s2 = red[4] + red[5] + red[6] + red[7];
    const float mu = s * (1.0f / 1024.0f);
    const float var = s2 * (1.0f / 1024.0f) - mu * mu;
    const float rstd = rsqrtf(var + 1e-5f);

    float4 gv = *(const float4*)(&gamma[tid * 4]);
    float4 bv = *(const float4*)(&beta[tid * 4]);
    float o0 = (v[0] - mu) * rstd * gv.x + bv.x;
    float o1 = (v[1] - mu) * rstd * gv.y + bv.y;
    float o2 = (v[2] - mu) * rstd * gv.z + bv.z;
    float o3 = (v[3] - mu) * rstd * gv.w + bv.w;

    if (OUT_F32) {
        float4 of = {o0, o1, o2, o3};
        *(float4*)((float*)Out + base) = of;
    } else {
        ushort_t ob[4] = {f2bf(o0), f2bf(o1), f2bf(o2), f2bf(o3)};
        *(uint2*)((ushort_t*)Out + base) = *(uint2*)ob;
    }
}

// ---------------------------------------------------------------------------
// Launch. Output fp32 (reference returns float32). ws:
//   Bq[0,8) Bk[8,24) Bv[24,40) Ba[40,48) Bh[48,56) Bx1[56,64) Bx2[64,72)
//   Bi=Bk[8,40)
// ---------------------------------------------------------------------------
extern "C" void kernel_launch(void* const* d_in, const int* in_sizes, int n_in,
                              void* d_out, int out_size, void* d_ws, size_t ws_size,
                              hipStream_t stream)
{
    const float* input = (const float*)d_in[0];
    const float* ctx   = (const float*)d_in[1];
    const float* mask  = (const float*)d_in[2];
    const float* cq_w = (const float*)d_in[3],  *cq_b = (const float*)d_in[4];
    const float* ck_w = (const float*)d_in[5],  *ck_b = (const float*)d_in[6];
    const float* cv_w = (const float*)d_in[7],  *cv_b = (const float*)d_in[8];
    const float* co_w = (const float*)d_in[9],  *co_b = (const float*)d_in[10];
    const float* co_g = (const float*)d_in[11], *co_be = (const float*)d_in[12];
    const float* sq_w = (const float*)d_in[13], *sq_b = (const float*)d_in[14];
    const float* sk_w = (const float*)d_in[15], *sk_b = (const float*)d_in[16];
    const float* sv_w = (const float*)d_in[17], *sv_b = (const float*)d_in[18];
    const float* so_w = (const float*)d_in[19], *so_b = (const float*)d_in[20];
    const float* so_g = (const float*)d_in[21], *so_be = (const float*)d_in[22];
    const float* fi_w = (const float*)d_in[23], *fi_b = (const float*)d_in[24];
    const float* fo_w = (const float*)d_in[25], *fo_b = (const float*)d_in[26];
    const float* fo_g = (const float*)d_in[27], *fo_be = (const float*)d_in[28];

    char* p = (char*)d_ws;
    const size_t MB = 1024 * 1024;
    ushort_t* Bq  = (ushort_t*)(p + 0 * MB);
    ushort_t* Bk  = (ushort_t*)(p + 8 * MB);
    ushort_t* Bv  = (ushort_t*)(p + 24 * MB);
    ushort_t* Ba  = (ushort_t*)(p + 40 * MB);
    ushort_t* Bh  = (ushort_t*)(p + 48 * MB);
    ushort_t* Bx1 = (ushort_t*)(p + 56 * MB);
    ushort_t* Bx2 = (ushort_t*)(p + 64 * MB);
    ushort_t* Bi  = Bk;   // FFN inter [8,40)

    const float scale = 0.125f;
    dim3 blk(256);

    // ---- cross attention ----
    gemm_kernel<0, false><<<dim3(8, 32), blk, 0, stream>>>(input, cq_w, cq_b, Bq, 4096, 1024, 1024);
    gemm_kernel<0, false><<<dim3(8, 64), blk, 0, stream>>>(ctx, ck_w, ck_b, Bk, 8192, 1024, 1024);
    gemm_kernel<0, false><<<dim3(8, 64), blk, 0, stream>>>(ctx, cv_w, cv_b, Bv, 8192, 1024, 1024);
    mfma_attn_kernel<<<dim3(16, 64), blk, 0, stream>>>(Bq, Bk, Bv, mask, Ba, 1024, 2048, scale);
    gemm_kernel<0, true><<<dim3(8, 32), blk, 0, stream>>>(Ba, co_w, co_b, Bh, 4096, 1024, 1024);
    ln_kernel<true, false><<<dim3(4096), blk, 0, stream>>>(Bh, input, co_g, co_be, Bx1);

    // ---- self attention ----
    gemm_kernel<0, true><<<dim3(8, 32), blk, 0, stream>>>(Bx1, sq_w, sq_b, Bq, 4096, 1024, 1024);
    gemm_kernel<0, true><<<dim3(8, 32), blk, 0, stream>>>(Bx1, sk_w, sk_b, Bk, 4096, 1024, 1024);
    gemm_kernel<0, true><<<dim3(8, 32), blk, 0, stream>>>(Bx1, sv_w, sv_b, Bv, 4096, 1024, 1024);
    mfma_attn_kernel<<<dim3(16, 64), blk, 0, stream>>>(Bq, Bk, Bv, nullptr, Ba, 1024, 1024, scale);
    gemm_kernel<0, true><<<dim3(8, 32), blk, 0, stream>>>(Ba, so_w, so_b, Bh, 4096, 1024, 1024);
    ln_kernel<false, false><<<dim3(4096), blk, 0, stream>>>(Bh, Bx1, so_g, so_be, Bx2);

    // ---- FFN ----
    gemm_kernel<2, true><<<dim3(32, 32), blk, 0, stream>>>(Bx2, fi_w, fi_b, Bi, 4096, 4096, 1024);
    gemm_kernel<0, true><<<dim3(8, 32), blk, 0, stream>>>(Bi, fo_w, fo_b, Bh, 4096, 1024, 4096);
    ln_kernel<false, true><<<dim3(4096), blk, 0, stream>>>(Bh, Bx2, fo_g, fo_be, (float*)d_out);
}